// Round 8
// baseline (417.774 us; speedup 1.0000x reference)
//
#include <hip/hip_runtime.h>

#define IC   32     // in_chunks
#define NE   64     // num_experts
#define D    128    // expert_size
#define IF   4096   // in_features
#define OF   8192   // out_features
#define TB   128    // batch rows per tile
#define KH   64     // K half-length (j-dimension split)
#define NBT  64     // number of batch tiles (8192 / 128)
#define NBLK 512    // persistent blocks = 2 per CU

typedef float vf4 __attribute__((ext_vector_type(4)));   // native vec for NT stores

// persistent fused kernel: 512 blocks grid-stride over 4096 (bt,e) slots.
// per slot: wave0 ternarizes expert column -> block does GEMM (active) or
// NT zero-fill (inactive). Identical arithmetic order to prior rounds.
__global__ __launch_bounds__(256, 2)
void moe_kernel(const float* __restrict__ x,
                const float* __restrict__ routing,
                const float* __restrict__ We,
                const float* __restrict__ noise,
                float* __restrict__ out) {
    __shared__ float sWe[KH * D];    // 32 KB, half-K of We[e], j-major, swizzled
    __shared__ float sXr[KH * TB];   // 32 KB, half-K of x_routed tile, swizzled
    __shared__ int   s_chunk[IC];
    __shared__ float s_csign[IC];
    __shared__ int   s_nnz;

    const int t = threadIdx.x;

    const int c4  = t & 31;   // fill: float4 lane in 128-float row
    const int r0  = t >> 5;   // fill: 0..7
    const int c4h = t & 15;   // stage: float4 lane in 64-float half-row
    const int r0h = t >> 4;   // stage: 0..15
    const int rg  = t & 15;   // gemm: r-block
    const int bg  = t >> 4;   // gemm: b-block

    float4* out4 = (float4*)out;
    vf4*    outv = (vf4*)out;
    const size_t orow4 = OF / 4;
    const float4* x4p = (const float4*)x;

    for (int slot = blockIdx.x; slot < NBT * NE; slot += NBLK) {
        const int bt = slot & (NBT - 1);
        const int e  = slot >> 6;

        // ---- wave 0: ternarize expert e's routing column, compact via ballot ----
        if (t < 64) {
            float sgn = 0.0f;
            if (t < IC) {
                float w  = routing[t * NE + e];
                float nz = noise[t * NE + e];
                float wn = __fadd_rn(w, __fmul_rn(0.1f, nz));   // exact: mul then add
                sgn = (wn < -0.5f) ? -1.0f : ((wn > 0.5f) ? 1.0f : 0.0f);
            }
            unsigned long long mask  = __ballot(sgn != 0.0f);
            unsigned long long below = mask & ((t == 0) ? 0ull : (~0ull >> (64 - t)));
            int pos = (int)__popcll(below);
            if (sgn != 0.0f) {               // ascending chunk order preserved
                s_chunk[pos] = t;
                s_csign[pos] = sgn;
            }
            if (t == 0) s_nnz = (int)__popcll(mask);
        }
        __syncthreads();
        const int nnz = s_nnz;

        if (nnz == 0) {
            // fill duty: zero this (bt,e) tile with nontemporal stores
            const vf4 z = (vf4){0.f, 0.f, 0.f, 0.f};
            #pragma unroll
            for (int p = 0; p < TB / 8; ++p) {
                size_t row = (size_t)(bt * TB + p * 8 + r0);
                __builtin_nontemporal_store(z, &outv[row * orow4 + e * (D / 4) + c4]);
            }
            __syncthreads();   // protect s_* for next slot
            continue;
        }

        const float4* We4 = (const float4*)(We + (size_t)e * D * D);

        float acc[8][8];
        #pragma unroll
        for (int a = 0; a < 8; ++a)
            #pragma unroll
            for (int c = 0; c < 8; ++c) acc[a][c] = 0.f;

        #pragma unroll
        for (int h = 0; h < 2; ++h) {
            if (h) __syncthreads();   // waves done reading previous half

            // stage We[e][:, h*64 .. ] transposed+swizzled:
            // (r, jl) -> sWe[jl*128 + ((r>>3)^((jl>>2)&15))*8 + (r&7)]
            #pragma unroll
            for (int p = 0; p < 8; ++p) {
                int r = p * 16 + r0h;
                float4 w4 = We4[r * (D / 4) + h * (KH / 4) + c4h];
                float wv[4] = {w4.x, w4.y, w4.z, w4.w};
                #pragma unroll
                for (int k = 0; k < 4; ++k) {
                    int jl  = c4h * 4 + k;
                    int blk = (r >> 3) ^ ((jl >> 2) & 15);
                    sWe[jl * D + blk * 8 + (r & 7)] = wv[k];
                }
            }

            // x_routed half-tile (ascending chunk order -> exact), swizzled
            #pragma unroll
            for (int p = 0; p < 8; ++p) {
                int b = p * 16 + r0h;
                size_t row = (size_t)(bt * TB + b);
                float4 acc4 = make_float4(0.f, 0.f, 0.f, 0.f);
                for (int m = 0; m < nnz; ++m) {
                    int   i  = s_chunk[m];
                    float sg = s_csign[m];
                    float4 v = x4p[row * (IF / 4) + i * (D / 4) + h * (KH / 4) + c4h];
                    acc4.x += sg * v.x; acc4.y += sg * v.y;
                    acc4.z += sg * v.z; acc4.w += sg * v.w;
                }
                float av[4] = {acc4.x, acc4.y, acc4.z, acc4.w};
                #pragma unroll
                for (int k = 0; k < 4; ++k) {
                    int jl  = c4h * 4 + k;
                    int blk = (b >> 3) ^ ((jl >> 2) & 15);
                    sXr[jl * TB + blk * 8 + (b & 7)] = av[k];
                }
            }
            __syncthreads();

            // register-tiled fp32 GEMM over this K-half (j ascending -> exact)
            #pragma unroll 2
            for (int jl = 0; jl < KH; ++jl) {
                const int sw = (jl >> 2) & 15;
                const float4* wr = (const float4*)&sWe[jl * D  + ((rg ^ sw) << 3)];
                const float4* xr = (const float4*)&sXr[jl * TB + ((bg ^ sw) << 3)];
                float4 w0 = wr[0], w1 = wr[1];
                float4 x0 = xr[0], x1 = xr[1];
                float wv[8] = {w0.x, w0.y, w0.z, w0.w, w1.x, w1.y, w1.z, w1.w};
                float xv[8] = {x0.x, x0.y, x0.z, x0.w, x1.x, x1.y, x1.z, x1.w};
                #pragma unroll
                for (int a = 0; a < 8; ++a)
                    #pragma unroll
                    for (int c = 0; c < 8; ++c)
                        acc[a][c] += wv[a] * xv[c];
            }
        }

        // epilogue: rows bt*TB + bg*8 + c, cols e*128 + rg*8 + {0..7}
        #pragma unroll
        for (int c = 0; c < 8; ++c) {
            size_t row  = (size_t)(bt * TB + bg * 8 + c);
            size_t base = row * orow4 + e * (D / 4) + rg * 2;
            out4[base]     = make_float4(acc[0][c], acc[1][c], acc[2][c], acc[3][c]);
            out4[base + 1] = make_float4(acc[4][c], acc[5][c], acc[6][c], acc[7][c]);
        }
        __syncthreads();   // protect s_* for next slot
    }
}

extern "C" void kernel_launch(void* const* d_in, const int* in_sizes, int n_in,
                              void* d_out, int out_size, void* d_ws, size_t ws_size,
                              hipStream_t stream) {
    const float* x       = (const float*)d_in[0];
    const float* routing = (const float*)d_in[1];
    const float* We      = (const float*)d_in[2];
    const float* noise   = (const float*)d_in[3];
    float* out = (float*)d_out;

    moe_kernel<<<NBLK, 256, 0, stream>>>(x, routing, We, noise, out);
}

// Round 9
// 393.197 us; speedup vs baseline: 1.0625x; 1.0625x over previous
//
#include <hip/hip_runtime.h>

#define IC   32     // in_chunks
#define NE   64     // num_experts
#define D    128    // expert_size
#define IF   4096   // in_features
#define OF   8192   // out_features
#define TB   128    // batch rows per block
#define KH   64     // K half-length (j-dimension split)

typedef float vf4 __attribute__((ext_vector_type(4)));   // native vec for NT stores

// single fused kernel: grid (B/TB, NE); each block ternarizes its own expert
// column (cheap, L2-resident) then does GEMM (active) or NT zero-fill (inactive)
// R7-proven: 391.6 us, absmax 0.0. R8 persistent variant regressed (+26 us,
// static partition kills dynamic load balancing) -> reverted.
__global__ __launch_bounds__(256, 2)
void moe_kernel(const float* __restrict__ x,
                const float* __restrict__ routing,
                const float* __restrict__ We,
                const float* __restrict__ noise,
                float* __restrict__ out) {
    __shared__ float sWe[KH * D];    // 32 KB, half-K of We[e], j-major, swizzled
    __shared__ float sXr[KH * TB];   // 32 KB, half-K of x_routed tile, j-major, swizzled
    __shared__ int   s_chunk[IC];
    __shared__ float s_csign[IC];
    __shared__ int   s_nnz;

    const int t  = threadIdx.x;
    const int bt = blockIdx.x;
    const int e  = blockIdx.y;

    // ---- wave 0: ternarize this expert's routing column, compact via ballot ----
    if (t < 64) {
        float sgn = 0.0f;
        if (t < IC) {
            float w  = routing[t * NE + e];
            float nz = noise[t * NE + e];
            float wn = __fadd_rn(w, __fmul_rn(0.1f, nz));   // exact: mul then add
            sgn = (wn < -0.5f) ? -1.0f : ((wn > 0.5f) ? 1.0f : 0.0f);
        }
        unsigned long long mask  = __ballot(sgn != 0.0f);
        unsigned long long below = mask & ((t == 0) ? 0ull : (~0ull >> (64 - t)));
        int pos = (int)__popcll(below);
        if (sgn != 0.0f) {               // ascending chunk order preserved
            s_chunk[pos] = t;
            s_csign[pos] = sgn;
        }
        if (t == 0) s_nnz = (int)__popcll(mask);
    }
    __syncthreads();
    const int nnz = s_nnz;

    float4* out4 = (float4*)out;
    const size_t orow4 = OF / 4;

    if (nnz == 0) {
        // fill duty: zero this (bt, e) output tile with nontemporal stores
        const int c4 = t & 31;
        const int r0 = t >> 5;
        vf4* outv = (vf4*)out;
        const vf4 z = (vf4){0.f, 0.f, 0.f, 0.f};
        #pragma unroll
        for (int p = 0; p < TB / 8; ++p) {
            size_t row = (size_t)(bt * TB + p * 8 + r0);
            __builtin_nontemporal_store(z, &outv[row * orow4 + e * (D / 4) + c4]);
        }
        return;
    }

    const int c4h = t & 15;   // float4 lane within a 64-float half-row
    const int r0h = t >> 4;   // 0..15
    const int rg  = t & 15;   // r-block for gemm
    const int bg  = t >> 4;   // b-block for gemm

    const float4* We4 = (const float4*)(We + (size_t)e * D * D);
    const float4* x4p = (const float4*)x;

    float acc[8][8];
    #pragma unroll
    for (int a = 0; a < 8; ++a)
        #pragma unroll
        for (int c = 0; c < 8; ++c) acc[a][c] = 0.f;

    #pragma unroll
    for (int h = 0; h < 2; ++h) {
        if (h) __syncthreads();   // all waves done reading previous half

        // stage We[e][:, h*64 : h*64+64] transposed+swizzled:
        // (r, jl) -> sWe[jl*128 + ((r>>3)^((jl>>2)&15))*8 + (r&7)]
        #pragma unroll
        for (int p = 0; p < 8; ++p) {
            int r = p * 16 + r0h;
            float4 w4 = We4[r * (D / 4) + h * (KH / 4) + c4h];
            float wv[4] = {w4.x, w4.y, w4.z, w4.w};
            #pragma unroll
            for (int k = 0; k < 4; ++k) {
                int jl  = c4h * 4 + k;
                int blk = (r >> 3) ^ ((jl >> 2) & 15);
                sWe[jl * D + blk * 8 + (r & 7)] = wv[k];
            }
        }

        // x_routed half-tile (ascending chunk order -> exact), transposed+swizzled
        #pragma unroll
        for (int p = 0; p < 8; ++p) {
            int b = p * 16 + r0h;
            size_t row = (size_t)(bt * TB + b);
            float4 acc4 = make_float4(0.f, 0.f, 0.f, 0.f);
            for (int m = 0; m < nnz; ++m) {
                int   i  = s_chunk[m];
                float sg = s_csign[m];
                float4 v = x4p[row * (IF / 4) + i * (D / 4) + h * (KH / 4) + c4h];
                acc4.x += sg * v.x; acc4.y += sg * v.y;
                acc4.z += sg * v.z; acc4.w += sg * v.w;
            }
            float av[4] = {acc4.x, acc4.y, acc4.z, acc4.w};
            #pragma unroll
            for (int k = 0; k < 4; ++k) {
                int jl  = c4h * 4 + k;
                int blk = (b >> 3) ^ ((jl >> 2) & 15);
                sXr[jl * TB + blk * 8 + (b & 7)] = av[k];
            }
        }
        __syncthreads();

        // register-tiled fp32 GEMM over this K-half (j ascending -> exact order)
        #pragma unroll 2
        for (int jl = 0; jl < KH; ++jl) {
            const int sw = (jl >> 2) & 15;
            const float4* wr = (const float4*)&sWe[jl * D  + ((rg ^ sw) << 3)];
            const float4* xr = (const float4*)&sXr[jl * TB + ((bg ^ sw) << 3)];
            float4 w0 = wr[0], w1 = wr[1];
            float4 x0 = xr[0], x1 = xr[1];
            float wv[8] = {w0.x, w0.y, w0.z, w0.w, w1.x, w1.y, w1.z, w1.w};
            float xv[8] = {x0.x, x0.y, x0.z, x0.w, x1.x, x1.y, x1.z, x1.w};
            #pragma unroll
            for (int a = 0; a < 8; ++a)
                #pragma unroll
                for (int c = 0; c < 8; ++c)
                    acc[a][c] += wv[a] * xv[c];
        }
    }

    // epilogue: rows bt*TB + bg*8 + c, cols e*128 + rg*8 + {0..7}
    #pragma unroll
    for (int c = 0; c < 8; ++c) {
        size_t row  = (size_t)(bt * TB + bg * 8 + c);
        size_t base = row * orow4 + e * (D / 4) + rg * 2;
        out4[base]     = make_float4(acc[0][c], acc[1][c], acc[2][c], acc[3][c]);
        out4[base + 1] = make_float4(acc[4][c], acc[5][c], acc[6][c], acc[7][c]);
    }
}

extern "C" void kernel_launch(void* const* d_in, const int* in_sizes, int n_in,
                              void* d_out, int out_size, void* d_ws, size_t ws_size,
                              hipStream_t stream) {
    const float* x       = (const float*)d_in[0];
    const float* routing = (const float*)d_in[1];
    const float* We      = (const float*)d_in[2];
    const float* noise   = (const float*)d_in[3];
    float* out = (float*)d_out;

    const int B = in_sizes[0] / IF;   // 8192
    dim3 grid(B / TB, NE);            // (64, 64)
    moe_kernel<<<grid, 256, 0, stream>>>(x, routing, We, noise, out);
}